// Round 1
// baseline (111.264 us; speedup 1.0000x reference)
//
#include <hip/hip_runtime.h>
#include <hip/hip_bf16.h>

// DotProductAttention: B=8, Nq=2048, Nk=2048, D=64, fp32 in/out, per-batch key mask.
// Round 1: flash-attention, 1 wave/block, 16 q-rows/wave, KV tile 32,
// mfma_f32_16x16x32_bf16 for QK^T and PV, fp32 online softmax.

typedef __attribute__((ext_vector_type(8))) short bf16x8;
typedef __attribute__((ext_vector_type(4))) float f32x4;

#define NQ 2048
#define NK 2048
#define DH 64
#define KVB 32

__device__ __forceinline__ unsigned short f2bf(float f) {
    union { float f; unsigned int u; } v; v.f = f;
    unsigned int u = v.u;
    u += 0x7FFFu + ((u >> 16) & 1u);   // RNE (inputs are normal randoms; NaN not expected)
    return (unsigned short)(u >> 16);
}

__device__ __forceinline__ float fast_exp2(float x) {
#if __has_builtin(__builtin_amdgcn_exp2f)
    return __builtin_amdgcn_exp2f(x);
#else
    return exp2f(x);
#endif
}

__global__ __launch_bounds__(64) void attn_fwd(
    const float* __restrict__ Q, const float* __restrict__ K,
    const float* __restrict__ V, const int* __restrict__ VL,
    float* __restrict__ O)
{
    // wave-local P buffer: 16 rows x 32 cols bf16, row stride 40 (80B) to spread banks
    __shared__ __align__(16) unsigned short Plds[16 * 40];

    const int bid = blockIdx.x;
    const int b  = bid >> 7;        // / (NQ/16 = 128)
    const int qt = bid & 127;
    const int q0 = qt * 16;
    const int lane = threadIdx.x;   // 0..63
    const int g = lane >> 4;        // 0..3 : K-chunk / row-group selector
    const int c = lane & 15;        // 0..15

    const float* Qb = Q + ((size_t)b * NQ + q0) * DH;
    const float* Kb = K + (size_t)b * NK * DH;
    const float* Vb = V + (size_t)b * NK * DH;
    const int vlen = VL[b];

    // Q fragments, scaled by 1/sqrt(64)=0.125 (exact power of 2, fold into Q)
    // A-layout: row = lane&15 (q), k = g*8 + e  (per 32-wide K-step ks)
    bf16x8 qf[2];
#pragma unroll
    for (int ks = 0; ks < 2; ++ks) {
        const float* src = Qb + (size_t)c * DH + ks * 32 + g * 8;
#pragma unroll
        for (int e = 0; e < 8; ++e)
            qf[ks][e] = (short)f2bf(src[e] * 0.125f);
    }

    f32x4 acc[4];                    // O accumulator, C-layout per d n-tile
#pragma unroll
    for (int nt = 0; nt < 4; ++nt) acc[nt] = (f32x4){0.f, 0.f, 0.f, 0.f};
    float m_run[4], l_run[4];
#pragma unroll
    for (int r = 0; r < 4; ++r) { m_run[r] = -3.0e38f; l_run[r] = 0.f; }

    const float L2E = 1.44269504088896341f;

    const int ntiles = (vlen + KVB - 1) / KVB;   // tiles past vlen contribute 0
    for (int kt = 0; kt < ntiles; ++kt) {
        const int kv0 = kt * KVB;

        // ---- S = Q K^T (two 16-col n-tiles, two 32-wide K-steps) ----
        f32x4 s[2] = {{0.f,0.f,0.f,0.f},{0.f,0.f,0.f,0.f}};
#pragma unroll
        for (int nt = 0; nt < 2; ++nt) {
            const int krow = kv0 + nt * 16 + c;      // B-frag: col = lane&15
            const float* kp = Kb + (size_t)krow * DH + g * 8;
#pragma unroll
            for (int ks = 0; ks < 2; ++ks) {
                bf16x8 kf;
#pragma unroll
                for (int e = 0; e < 8; ++e) kf[e] = (short)f2bf(kp[ks * 32 + e]);
                s[nt] = __builtin_amdgcn_mfma_f32_16x16x32_bf16(qf[ks], kf, s[nt], 0, 0, 0);
            }
        }

        // ---- mask key positions >= vlen ----
        const bool msk0 = (kv0 + c)      >= vlen;
        const bool msk1 = (kv0 + 16 + c) >= vlen;
#pragma unroll
        for (int r = 0; r < 4; ++r) {
            if (msk0) s[0][r] = -1e30f;
            if (msk1) s[1][r] = -1e30f;
        }

        // ---- row max across the 16 lanes of this row group ----
        float tmax[4];
#pragma unroll
        for (int r = 0; r < 4; ++r) tmax[r] = fmaxf(s[0][r], s[1][r]);
#pragma unroll
        for (int mbit = 1; mbit < 16; mbit <<= 1)
#pragma unroll
            for (int r = 0; r < 4; ++r)
                tmax[r] = fmaxf(tmax[r], __shfl_xor(tmax[r], mbit));

        // ---- online softmax update ----
        float p0[4], p1[4];
#pragma unroll
        for (int r = 0; r < 4; ++r) {
            const float mn = fmaxf(m_run[r], tmax[r]);
            const float sc = fast_exp2((m_run[r] - mn) * L2E);  // 0 on first tile
            m_run[r] = mn;
            p0[r] = fast_exp2((s[0][r] - mn) * L2E);            // masked -> 0 exactly
            p1[r] = fast_exp2((s[1][r] - mn) * L2E);
            l_run[r] = l_run[r] * sc + p0[r] + p1[r];
#pragma unroll
            for (int nt = 0; nt < 4; ++nt) acc[nt][r] *= sc;
        }

        // ---- P: C-layout -> LDS row-major [16][40] -> A-layout frags ----
#pragma unroll
        for (int r = 0; r < 4; ++r) {
            Plds[(4 * g + r) * 40 + c]      = f2bf(p0[r]);
            Plds[(4 * g + r) * 40 + 16 + c] = f2bf(p1[r]);
        }
        asm volatile("s_waitcnt lgkmcnt(0)" ::: "memory");  // wave-local LDS visibility
        const bf16x8 pa = *reinterpret_cast<const bf16x8*>(&Plds[c * 40 + g * 8]);

        // ---- O += P V  (4 d n-tiles; B-frag: V[kv0+g*8+e][nt*16+c]) ----
#pragma unroll
        for (int nt = 0; nt < 4; ++nt) {
            bf16x8 vf;
#pragma unroll
            for (int e = 0; e < 8; ++e) {
                const float v = Vb[(size_t)(kv0 + 8 * g + e) * DH + nt * 16 + c];
                vf[e] = (short)f2bf(v);
            }
            acc[nt] = __builtin_amdgcn_mfma_f32_16x16x32_bf16(pa, vf, acc[nt], 0, 0, 0);
        }
    }

    // ---- final: reduce l across the 16 lanes, normalize, store ----
#pragma unroll
    for (int mbit = 1; mbit < 16; mbit <<= 1)
#pragma unroll
        for (int r = 0; r < 4; ++r)
            l_run[r] += __shfl_xor(l_run[r], mbit);

    float* Ob = O + ((size_t)b * NQ + q0) * DH;
#pragma unroll
    for (int r = 0; r < 4; ++r) {
        const float inv = 1.0f / l_run[r];
#pragma unroll
        for (int nt = 0; nt < 4; ++nt)
            Ob[(size_t)(4 * g + r) * DH + nt * 16 + c] = acc[nt][r] * inv;
    }
}

extern "C" void kernel_launch(void* const* d_in, const int* in_sizes, int n_in,
                              void* d_out, int out_size, void* d_ws, size_t ws_size,
                              hipStream_t stream) {
    const float* Q  = (const float*)d_in[0];
    const float* K  = (const float*)d_in[1];
    const float* V  = (const float*)d_in[2];
    const int*   VL = (const int*)d_in[3];
    float* O = (float*)d_out;

    const int B = 8;
    const int nblocks = B * (NQ / 16);   // 1024 blocks, 1 wave each
    attn_fwd<<<nblocks, 64, 0, stream>>>(Q, K, V, VL, O);
}

// Round 2
// 74.544 us; speedup vs baseline: 1.4926x; 1.4926x over previous
//
#include <hip/hip_runtime.h>
#include <hip/hip_bf16.h>

// DotProductAttention: B=8, Nq=2048, Nk=2048, D=64, fp32 in/out, per-batch key mask.
// Round 2: prep-converted bf16 K / transposed V, split-KV x4 flash attention + merge.

typedef __attribute__((ext_vector_type(8))) short bf16x8;
typedef __attribute__((ext_vector_type(4))) float f32x4;

#define NQ 2048
#define NK 2048
#define DH 64
#define NB 8
#define NSPLIT 4
#define SPLIT_LEN 512
#define KVB 64

__device__ __forceinline__ unsigned short f2bf(float f) {
    union { float f; unsigned int u; } v; v.f = f;
    unsigned int u = v.u;
    u += 0x7FFFu + ((u >> 16) & 1u);   // RNE
    return (unsigned short)(u >> 16);
}

__device__ __forceinline__ float fast_exp2(float x) {
#if __has_builtin(__builtin_amdgcn_exp2f)
    return __builtin_amdgcn_exp2f(x);
#else
    return exp2f(x);
#endif
}

// ---------------- prep: K fp32 -> bf16 (same layout) ----------------
__global__ __launch_bounds__(256) void prep_k(const float* __restrict__ K,
                                              unsigned short* __restrict__ Kbf) {
    const size_t idx = ((size_t)blockIdx.x * 256 + threadIdx.x) * 8;
    const float4 a = *reinterpret_cast<const float4*>(K + idx);
    const float4 b = *reinterpret_cast<const float4*>(K + idx + 4);
    bf16x8 o;
    o[0] = (short)f2bf(a.x); o[1] = (short)f2bf(a.y);
    o[2] = (short)f2bf(a.z); o[3] = (short)f2bf(a.w);
    o[4] = (short)f2bf(b.x); o[5] = (short)f2bf(b.y);
    o[6] = (short)f2bf(b.z); o[7] = (short)f2bf(b.w);
    *reinterpret_cast<bf16x8*>(Kbf + idx) = o;
}

// ---------------- prep: V fp32 [k][d] -> bf16 Vt [d][k] ----------------
__global__ __launch_bounds__(256) void prep_vt(const float* __restrict__ V,
                                               unsigned short* __restrict__ Vt) {
    __shared__ unsigned short T[64][65];
    const int b  = blockIdx.x >> 5;
    const int k0 = (blockIdx.x & 31) * 64;
    const int t  = threadIdx.x;
    // load 64x64 fp32 tile, convert, store to LDS
    const int r  = t >> 2;
    const int cb = (t & 3) * 16;
    const float* src = V + ((size_t)(b * NK + k0 + r)) * DH + cb;
#pragma unroll
    for (int j = 0; j < 16; ++j) T[r][cb + j] = f2bf(src[j]);
    __syncthreads();
    // write transposed: Vt[b][d][k0+k], 8 contiguous k per chunk
    unsigned short* dstb = Vt + (size_t)b * DH * NK;
#pragma unroll
    for (int i = 0; i < 2; ++i) {
        const int cc = t + i * 256;
        const int d  = cc >> 3;
        const int kb = (cc & 7) * 8;
        bf16x8 o;
#pragma unroll
        for (int j = 0; j < 8; ++j) o[j] = (short)T[kb + j][d];
        *reinterpret_cast<bf16x8*>(dstb + (size_t)d * NK + k0 + kb) = o;
    }
}

// ---------------- main: split-KV flash attention partials ----------------
__global__ __launch_bounds__(64) void attn_split(
    const float* __restrict__ Q, const unsigned short* __restrict__ Kbf,
    const unsigned short* __restrict__ Vt, const int* __restrict__ VL,
    float2* __restrict__ ml, float* __restrict__ Opart)
{
    __shared__ __align__(16) unsigned short Plds[16 * 72];

    const int bid = blockIdx.x;
    const int b   = bid >> 9;          // 512 blocks per batch
    const int s   = (bid >> 7) & (NSPLIT - 1);
    const int qt  = bid & 127;
    const int vlen  = VL[b];
    const int kv_lo = s * SPLIT_LEN;
    if (kv_lo >= vlen) return;         // inactive split: merge skips it
    const int kv_hi = min(vlen, kv_lo + SPLIT_LEN);

    const int lane = threadIdx.x;
    const int g = lane >> 4;           // 0..3
    const int c = lane & 15;           // 0..15

    const float* Qb = Q + ((size_t)b * NQ + qt * 16) * DH;
    const unsigned short* Kb = Kbf + (size_t)b * NK * DH;
    const unsigned short* Vb = Vt  + (size_t)b * DH * NK;

    // Q A-frags (row = c, k = ks*32 + g*8 + e), scaled by 1/sqrt(64)
    bf16x8 qf[2];
#pragma unroll
    for (int ks = 0; ks < 2; ++ks) {
        const float* src = Qb + (size_t)c * DH + ks * 32 + g * 8;
#pragma unroll
        for (int e = 0; e < 8; ++e) qf[ks][e] = (short)f2bf(src[e] * 0.125f);
    }

    f32x4 acc[4];
#pragma unroll
    for (int nt = 0; nt < 4; ++nt) acc[nt] = (f32x4){0.f, 0.f, 0.f, 0.f};
    float m_run[4], l_run[4];
#pragma unroll
    for (int r = 0; r < 4; ++r) { m_run[r] = -3.0e38f; l_run[r] = 0.f; }

    const float L2E = 1.44269504088896341f;
    const int ntiles = (kv_hi - kv_lo + KVB - 1) >> 6;

    for (int kt = 0; kt < ntiles; ++kt) {
        const int kv0 = kv_lo + (kt << 6);

        // ---- S = Q K^T : 4 n-tiles x 2 k-steps ----
        f32x4 sv[4];
#pragma unroll
        for (int nt = 0; nt < 4; ++nt) sv[nt] = (f32x4){0.f, 0.f, 0.f, 0.f};
#pragma unroll
        for (int nt = 0; nt < 4; ++nt) {
            const unsigned short* kp = Kb + (size_t)(kv0 + nt * 16 + c) * DH + g * 8;
#pragma unroll
            for (int ks = 0; ks < 2; ++ks) {
                const bf16x8 kf = *reinterpret_cast<const bf16x8*>(kp + ks * 32);
                sv[nt] = __builtin_amdgcn_mfma_f32_16x16x32_bf16(qf[ks], kf, sv[nt], 0, 0, 0);
            }
        }

        // ---- prefetch V B-frags (in flight during softmax) ----
        bf16x8 vf[2][4];
#pragma unroll
        for (int ks = 0; ks < 2; ++ks)
#pragma unroll
            for (int nt = 0; nt < 4; ++nt)
                vf[ks][nt] = *reinterpret_cast<const bf16x8*>(
                    Vb + (size_t)(nt * 16 + c) * NK + kv0 + ks * 32 + g * 8);

        // ---- mask (only possibly-partial last tile) ----
        if (kv0 + KVB > kv_hi) {
#pragma unroll
            for (int nt = 0; nt < 4; ++nt) {
                const bool msk = (kv0 + nt * 16 + c) >= vlen;
                if (msk) {
#pragma unroll
                    for (int r = 0; r < 4; ++r) sv[nt][r] = -1e30f;
                }
            }
        }

        // ---- online softmax ----
        float tmax[4];
#pragma unroll
        for (int r = 0; r < 4; ++r)
            tmax[r] = fmaxf(fmaxf(sv[0][r], sv[1][r]), fmaxf(sv[2][r], sv[3][r]));
#pragma unroll
        for (int mbit = 1; mbit < 16; mbit <<= 1)
#pragma unroll
            for (int r = 0; r < 4; ++r)
                tmax[r] = fmaxf(tmax[r], __shfl_xor(tmax[r], mbit));

        float p[4][4];
#pragma unroll
        for (int r = 0; r < 4; ++r) {
            const float mn = fmaxf(m_run[r], tmax[r]);
            const float sc = fast_exp2((m_run[r] - mn) * L2E);
            m_run[r] = mn;
            float rs = 0.f;
#pragma unroll
            for (int nt = 0; nt < 4; ++nt) {
                p[nt][r] = fast_exp2((sv[nt][r] - mn) * L2E);
                rs += p[nt][r];
            }
            l_run[r] = l_run[r] * sc + rs;
#pragma unroll
            for (int nt = 0; nt < 4; ++nt) acc[nt][r] *= sc;
        }

        // ---- P: C-layout -> LDS [16][72] -> A-frags ----
#pragma unroll
        for (int r = 0; r < 4; ++r)
#pragma unroll
            for (int nt = 0; nt < 4; ++nt)
                Plds[(4 * g + r) * 72 + nt * 16 + c] = f2bf(p[nt][r]);
        asm volatile("s_waitcnt lgkmcnt(0)" ::: "memory");
        const bf16x8 pa0 = *reinterpret_cast<const bf16x8*>(&Plds[c * 72 + g * 8]);
        const bf16x8 pa1 = *reinterpret_cast<const bf16x8*>(&Plds[c * 72 + 32 + g * 8]);

        // ---- O += P V ----
#pragma unroll
        for (int nt = 0; nt < 4; ++nt)
            acc[nt] = __builtin_amdgcn_mfma_f32_16x16x32_bf16(pa0, vf[0][nt], acc[nt], 0, 0, 0);
#pragma unroll
        for (int nt = 0; nt < 4; ++nt)
            acc[nt] = __builtin_amdgcn_mfma_f32_16x16x32_bf16(pa1, vf[1][nt], acc[nt], 0, 0, 0);
    }

    // ---- reduce l across 16 lanes; write partials (unnormalized) ----
#pragma unroll
    for (int mbit = 1; mbit < 16; mbit <<= 1)
#pragma unroll
        for (int r = 0; r < 4; ++r)
            l_run[r] += __shfl_xor(l_run[r], mbit);

    const size_t pbase = (size_t)(b * NSPLIT + s) * 128 + qt;
    if (c == 0) {
#pragma unroll
        for (int r = 0; r < 4; ++r)
            ml[pbase * 16 + 4 * g + r] = make_float2(m_run[r], l_run[r]);
    }
    float* op = Opart + pbase * 1024;
#pragma unroll
    for (int r = 0; r < 4; ++r)
#pragma unroll
        for (int nt = 0; nt < 4; ++nt)
            op[(4 * g + r) * 64 + nt * 16 + c] = acc[nt][r];
}

// ---------------- merge the active splits ----------------
__global__ __launch_bounds__(64) void attn_merge(
    const float2* __restrict__ ml, const float* __restrict__ Opart,
    const int* __restrict__ VL, float* __restrict__ O)
{
    const int bid = blockIdx.x;
    const int b  = bid >> 7;
    const int qt = bid & 127;
    const int lane = threadIdx.x;
    const int r  = lane >> 2;
    const int d0 = (lane & 3) * 16;
    const int vlen = VL[b];
    const int nact = min(NSPLIT, (vlen + SPLIT_LEN - 1) / SPLIT_LEN);
    const float L2E = 1.44269504088896341f;

    float M = -3.0e38f;
    float2 mls[NSPLIT];
    for (int s = 0; s < nact; ++s) {
        mls[s] = ml[((size_t)(b * NSPLIT + s) * 128 + qt) * 16 + r];
        M = fmaxf(M, mls[s].x);
    }
    float L = 0.f;
    float4 accv[4] = {{0,0,0,0},{0,0,0,0},{0,0,0,0},{0,0,0,0}};
    for (int s = 0; s < nact; ++s) {
        const float w = fast_exp2((mls[s].x - M) * L2E);
        L += w * mls[s].y;
        const float4* src = reinterpret_cast<const float4*>(
            Opart + ((size_t)(b * NSPLIT + s) * 128 + qt) * 1024 + r * 64 + d0);
#pragma unroll
        for (int j = 0; j < 4; ++j) {
            accv[j].x += w * src[j].x; accv[j].y += w * src[j].y;
            accv[j].z += w * src[j].z; accv[j].w += w * src[j].w;
        }
    }
    const float inv = 1.0f / L;
    float4* dst = reinterpret_cast<float4*>(O + ((size_t)(b * NQ + qt * 16 + r)) * DH + d0);
#pragma unroll
    for (int j = 0; j < 4; ++j) {
        float4 o = accv[j];
        o.x *= inv; o.y *= inv; o.z *= inv; o.w *= inv;
        dst[j] = o;
    }
}

// ---------------- round-1 fallback (direct fp32 loads), used if ws too small ----------------
__global__ __launch_bounds__(64) void attn_fwd(
    const float* __restrict__ Q, const float* __restrict__ K,
    const float* __restrict__ V, const int* __restrict__ VL,
    float* __restrict__ O)
{
    __shared__ __align__(16) unsigned short Plds[16 * 40];
    const int bid = blockIdx.x;
    const int b  = bid >> 7;
    const int qt = bid & 127;
    const int q0 = qt * 16;
    const int lane = threadIdx.x;
    const int g = lane >> 4;
    const int c = lane & 15;
    const float* Qb = Q + ((size_t)b * NQ + q0) * DH;
    const float* Kb = K + (size_t)b * NK * DH;
    const float* Vb = V + (size_t)b * NK * DH;
    const int vlen = VL[b];
    bf16x8 qf[2];
#pragma unroll
    for (int ks = 0; ks < 2; ++ks) {
        const float* src = Qb + (size_t)c * DH + ks * 32 + g * 8;
#pragma unroll
        for (int e = 0; e < 8; ++e) qf[ks][e] = (short)f2bf(src[e] * 0.125f);
    }
    f32x4 acc[4];
#pragma unroll
    for (int nt = 0; nt < 4; ++nt) acc[nt] = (f32x4){0.f,0.f,0.f,0.f};
    float m_run[4], l_run[4];
#pragma unroll
    for (int r = 0; r < 4; ++r) { m_run[r] = -3.0e38f; l_run[r] = 0.f; }
    const float L2E = 1.44269504088896341f;
    const int ntiles = (vlen + 31) / 32;
    for (int kt = 0; kt < ntiles; ++kt) {
        const int kv0 = kt * 32;
        f32x4 s[2] = {{0.f,0.f,0.f,0.f},{0.f,0.f,0.f,0.f}};
#pragma unroll
        for (int nt = 0; nt < 2; ++nt) {
            const float* kp = Kb + (size_t)(kv0 + nt * 16 + c) * DH + g * 8;
#pragma unroll
            for (int ks = 0; ks < 2; ++ks) {
                bf16x8 kf;
#pragma unroll
                for (int e = 0; e < 8; ++e) kf[e] = (short)f2bf(kp[ks * 32 + e]);
                s[nt] = __builtin_amdgcn_mfma_f32_16x16x32_bf16(qf[ks], kf, s[nt], 0, 0, 0);
            }
        }
        const bool msk0 = (kv0 + c)      >= vlen;
        const bool msk1 = (kv0 + 16 + c) >= vlen;
#pragma unroll
        for (int r = 0; r < 4; ++r) {
            if (msk0) s[0][r] = -1e30f;
            if (msk1) s[1][r] = -1e30f;
        }
        float tmax[4];
#pragma unroll
        for (int r = 0; r < 4; ++r) tmax[r] = fmaxf(s[0][r], s[1][r]);
#pragma unroll
        for (int mbit = 1; mbit < 16; mbit <<= 1)
#pragma unroll
            for (int r = 0; r < 4; ++r)
                tmax[r] = fmaxf(tmax[r], __shfl_xor(tmax[r], mbit));
        float p0[4], p1[4];
#pragma unroll
        for (int r = 0; r < 4; ++r) {
            const float mn = fmaxf(m_run[r], tmax[r]);
            const float sc = fast_exp2((m_run[r] - mn) * L2E);
            m_run[r] = mn;
            p0[r] = fast_exp2((s[0][r] - mn) * L2E);
            p1[r] = fast_exp2((s[1][r] - mn) * L2E);
            l_run[r] = l_run[r] * sc + p0[r] + p1[r];
#pragma unroll
            for (int nt = 0; nt < 4; ++nt) acc[nt][r] *= sc;
        }
#pragma unroll
        for (int r = 0; r < 4; ++r) {
            Plds[(4 * g + r) * 40 + c]      = f2bf(p0[r]);
            Plds[(4 * g + r) * 40 + 16 + c] = f2bf(p1[r]);
        }
        asm volatile("s_waitcnt lgkmcnt(0)" ::: "memory");
        const bf16x8 pa = *reinterpret_cast<const bf16x8*>(&Plds[c * 40 + g * 8]);
#pragma unroll
        for (int nt = 0; nt < 4; ++nt) {
            bf16x8 vf;
#pragma unroll
            for (int e = 0; e < 8; ++e)
                vf[e] = (short)f2bf(Vb[(size_t)(kv0 + 8 * g + e) * DH + nt * 16 + c]);
            acc[nt] = __builtin_amdgcn_mfma_f32_16x16x32_bf16(pa, vf, acc[nt], 0, 0, 0);
        }
    }
#pragma unroll
    for (int mbit = 1; mbit < 16; mbit <<= 1)
#pragma unroll
        for (int r = 0; r < 4; ++r)
            l_run[r] += __shfl_xor(l_run[r], mbit);
    float* Ob = O + ((size_t)b * NQ + q0) * DH;
#pragma unroll
    for (int r = 0; r < 4; ++r) {
        const float inv = 1.0f / l_run[r];
#pragma unroll
        for (int nt = 0; nt < 4; ++nt)
            Ob[(size_t)(4 * g + r) * DH + nt * 16 + c] = acc[nt][r] * inv;
    }
}

extern "C" void kernel_launch(void* const* d_in, const int* in_sizes, int n_in,
                              void* d_out, int out_size, void* d_ws, size_t ws_size,
                              hipStream_t stream) {
    const float* Q  = (const float*)d_in[0];
    const float* K  = (const float*)d_in[1];
    const float* V  = (const float*)d_in[2];
    const int*   VL = (const int*)d_in[3];
    float* O = (float*)d_out;

    // ws layout
    const size_t KB_OFF = 0;                       // 2 MB  bf16 K
    const size_t VT_OFF = 2097152;                 // 2 MB  bf16 V^T
    const size_t ML_OFF = 4194304;                 // 512 KB float2 (m,l)
    const size_t OP_OFF = 4718592;                 // 16 MB fp32 O partials
    const size_t NEED   = OP_OFF + (size_t)NB * NSPLIT * 128 * 1024 * 4;

    if (ws_size >= NEED) {
        char* w = (char*)d_ws;
        unsigned short* Kbf  = (unsigned short*)(w + KB_OFF);
        unsigned short* Vtp  = (unsigned short*)(w + VT_OFF);
        float2*         mlp  = (float2*)(w + ML_OFF);
        float*          Opart = (float*)(w + OP_OFF);

        prep_k <<<512, 256, 0, stream>>>(K, Kbf);
        prep_vt<<<256, 256, 0, stream>>>(V, Vtp);
        attn_split<<<NB * NSPLIT * 128, 64, 0, stream>>>(Q, Kbf, Vtp, VL, mlp, Opart);
        attn_merge<<<NB * 128, 64, 0, stream>>>(mlp, Opart, VL, O);
    } else {
        attn_fwd<<<NB * 128, 64, 0, stream>>>(Q, K, V, VL, O);
    }
}

// Round 5
// 72.357 us; speedup vs baseline: 1.5377x; 1.0302x over previous
//
#include <hip/hip_runtime.h>
#include <hip/hip_bf16.h>

// DotProductAttention: B=8, Nq=2048, Nk=2048, D=64, fp32 in/out, per-batch key mask.
// Round 5: R4 structure with the P-tile LDS overflow fixed (PSTRIDE 20 -> 36).
// Swapped QK^T (S^T in regs, lane-local softmax), per-wave LDS P-repack,
// split-KV x8, 4-wave blocks, bf16 partials, fused prep.

typedef __attribute__((ext_vector_type(8))) short bf16x8;
typedef __attribute__((ext_vector_type(8))) unsigned short u16x8;
typedef __attribute__((ext_vector_type(4))) float f32x4;

#define NQ 2048
#define NK 2048
#define DH 64
#define NB 8
#define NSPLIT 8
#define SPLIT_LEN 256
#define KVB 64
#define L2E 1.44269504088896341f
#define PSTRIDE 36   // u32 row stride: 32 keypairs + 4 pad; c*36+4g stays 16B-aligned

__device__ __forceinline__ unsigned short f2bf(float f) {
    union { float f; unsigned int u; } v; v.f = f;
    unsigned int u = v.u;
    u += 0x7FFFu + ((u >> 16) & 1u);   // RNE
    return (unsigned short)(u >> 16);
}
__device__ __forceinline__ float bf2f(unsigned short u) {
    union { unsigned int u; float f; } v; v.u = ((unsigned int)u) << 16; return v.f;
}
__device__ __forceinline__ unsigned int pack_bf2(float lo, float hi) {
    return ((unsigned int)f2bf(hi) << 16) | (unsigned int)f2bf(lo);
}
__device__ __forceinline__ float fast_exp2(float x) {
#if __has_builtin(__builtin_amdgcn_exp2f)
    return __builtin_amdgcn_exp2f(x);
#else
    return exp2f(x);
#endif
}

// ---------------- fused prep: K->bf16 (blocks 0..511), V->Vt bf16 (blocks 512..767) ----------------
__global__ __launch_bounds__(256) void prep(const float* __restrict__ K,
                                            const float* __restrict__ V,
                                            unsigned short* __restrict__ Kbf,
                                            unsigned short* __restrict__ Vt) {
    if (blockIdx.x < 512) {
        const size_t idx = ((size_t)blockIdx.x * 256 + threadIdx.x) * 8;
        const float4 a = *reinterpret_cast<const float4*>(K + idx);
        const float4 b = *reinterpret_cast<const float4*>(K + idx + 4);
        bf16x8 o;
        o[0] = (short)f2bf(a.x); o[1] = (short)f2bf(a.y);
        o[2] = (short)f2bf(a.z); o[3] = (short)f2bf(a.w);
        o[4] = (short)f2bf(b.x); o[5] = (short)f2bf(b.y);
        o[6] = (short)f2bf(b.z); o[7] = (short)f2bf(b.w);
        *reinterpret_cast<bf16x8*>(Kbf + idx) = o;
    } else {
        __shared__ unsigned short T[64][65];
        const int bid2 = blockIdx.x - 512;
        const int b  = bid2 >> 5;
        const int k0 = (bid2 & 31) * 64;
        const int t  = threadIdx.x;
        const int r  = t >> 2;
        const int cb = (t & 3) * 16;
        const float* src = V + ((size_t)(b * NK + k0 + r)) * DH + cb;
#pragma unroll
        for (int j = 0; j < 16; ++j) T[r][cb + j] = f2bf(src[j]);
        __syncthreads();
        unsigned short* dstb = Vt + (size_t)b * DH * NK;
#pragma unroll
        for (int i = 0; i < 2; ++i) {
            const int cc = t + i * 256;
            const int d  = cc >> 3;
            const int kb = (cc & 7) * 8;
            bf16x8 o;
#pragma unroll
            for (int j = 0; j < 8; ++j) o[j] = (short)T[kb + j][d];
            *reinterpret_cast<bf16x8*>(dstb + (size_t)d * NK + k0 + kb) = o;
        }
    }
}

// ---------------- main: split-KV partials, swapped-QK^T, per-wave LDS P-repack ----------------
__global__ __launch_bounds__(256) void attn_split(
    const float* __restrict__ Q, const unsigned short* __restrict__ Kbf,
    const unsigned short* __restrict__ Vt, const int* __restrict__ VL,
    float2* __restrict__ ml, unsigned short* __restrict__ Opart)
{
    __shared__ __align__(16) unsigned int Pl[4][16 * PSTRIDE];

    const int bid = blockIdx.x;
    const int b  = bid >> 8;                 // 256 blocks per batch
    const int s  = (bid >> 5) & (NSPLIT - 1);
    const int qg = bid & 31;
    const int vlen  = VL[b];
    const int kv_lo = s * SPLIT_LEN;
    if (kv_lo >= vlen) return;               // inactive split: merge skips it
    const int kv_hi = min(vlen, kv_lo + SPLIT_LEN);

    const int tid  = threadIdx.x;
    const int wv   = tid >> 6;
    const int lane = tid & 63;
    const int g = lane >> 4;                 // 0..3
    const int c = lane & 15;                 // 0..15
    const int qt = qg * 4 + wv;              // q-tile 0..127

    const float* Qb = Q + ((size_t)b * NQ + qt * 16) * DH;
    const unsigned short* Kb = Kbf + (size_t)b * NK * DH;
    const unsigned short* Vb = Vt  + (size_t)b * DH * NK;
    unsigned int* Pw = &Pl[wv][0];

    // Q B-frags: B[k = ks*32+g*8+e][n = c], value Q[q=c][d=k]; scale 1/8 folded in
    bf16x8 qf[2];
#pragma unroll
    for (int ks = 0; ks < 2; ++ks) {
        const float* src = Qb + (size_t)c * DH + ks * 32 + g * 8;
#pragma unroll
        for (int e = 0; e < 8; ++e) qf[ks][e] = (short)f2bf(src[e] * 0.125f);
    }

    f32x4 acc[4];                            // acc[ntd][r] = O[q=4g+r][d=ntd*16+c]
#pragma unroll
    for (int nt = 0; nt < 4; ++nt) acc[nt] = (f32x4){0.f, 0.f, 0.f, 0.f};
    float m_run = -3.0e38f, l_run = 0.f;     // per-lane: q = c

    const int ntiles = (kv_hi - kv_lo + KVB - 1) >> 6;
    for (int kt = 0; kt < ntiles; ++kt) {
        const int kv0 = kv_lo + (kt << 6);

        // ---- S^T: sv[nt][r] = S[q=c][key=kv0+nt*16+4g+r] ----
        f32x4 sv[4];
#pragma unroll
        for (int nt = 0; nt < 4; ++nt) {
            const unsigned short* kp = Kb + (size_t)(kv0 + nt * 16 + c) * DH + g * 8;
            const bf16x8 kf0 = *reinterpret_cast<const bf16x8*>(kp);
            const bf16x8 kf1 = *reinterpret_cast<const bf16x8*>(kp + 32);
            f32x4 t = (f32x4){0.f, 0.f, 0.f, 0.f};
            t = __builtin_amdgcn_mfma_f32_16x16x32_bf16(kf0, qf[0], t, 0, 0, 0);
            t = __builtin_amdgcn_mfma_f32_16x16x32_bf16(kf1, qf[1], t, 0, 0, 0);
            sv[nt] = t;
        }

        // ---- prefetch V B-frags: vf[ks2][ntd][e] = V[kv0+ks2*32+g*8+e][ntd*16+c] ----
        bf16x8 vf[2][4];
#pragma unroll
        for (int ks2 = 0; ks2 < 2; ++ks2)
#pragma unroll
            for (int ntd = 0; ntd < 4; ++ntd)
                vf[ks2][ntd] = *reinterpret_cast<const bf16x8*>(
                    Vb + (size_t)(ntd * 16 + c) * NK + kv0 + ks2 * 32 + g * 8);

        // ---- mask key >= vlen (last tile only) ----
        if (kv0 + KVB > kv_hi) {
#pragma unroll
            for (int nt = 0; nt < 4; ++nt)
#pragma unroll
                for (int r = 0; r < 4; ++r)
                    if (kv0 + nt * 16 + 4 * g + r >= vlen) sv[nt][r] = -1e30f;
        }

        // ---- row max: 15 local fmax + 2 cross-group shuffles ----
        float tmax = fmaxf(fmaxf(fmaxf(sv[0][0], sv[0][1]), fmaxf(sv[0][2], sv[0][3])),
                           fmaxf(fmaxf(sv[1][0], sv[1][1]), fmaxf(sv[1][2], sv[1][3])));
        tmax = fmaxf(tmax, fmaxf(fmaxf(fmaxf(sv[2][0], sv[2][1]), fmaxf(sv[2][2], sv[2][3])),
                                 fmaxf(fmaxf(sv[3][0], sv[3][1]), fmaxf(sv[3][2], sv[3][3]))));
        tmax = fmaxf(tmax, __shfl_xor(tmax, 16));
        tmax = fmaxf(tmax, __shfl_xor(tmax, 32));

        const float mn = fmaxf(m_run, tmax);
        const float sc = fast_exp2((m_run - mn) * L2E);
        m_run = mn;

        float rs = 0.f;
#pragma unroll
        for (int nt = 0; nt < 4; ++nt)
#pragma unroll
            for (int r = 0; r < 4; ++r) {
                const float p = fast_exp2((sv[nt][r] - mn) * L2E);
                sv[nt][r] = p;
                rs += p;
            }
        l_run = l_run * sc + rs;

        // ---- rescale O: sc for q=4g+r pulled from lane 4g+r (its c == 4g+r) ----
        float scq[4];
#pragma unroll
        for (int r = 0; r < 4; ++r)
            scq[r] = __int_as_float(__builtin_amdgcn_ds_bpermute((4 * g + r) * 4,
                                                                 __float_as_int(sc)));
#pragma unroll
        for (int ntd = 0; ntd < 4; ++ntd)
#pragma unroll
            for (int r = 0; r < 4; ++r) acc[ntd][r] *= scq[r];

        // ---- P repack via per-wave LDS: write [q=c][keypair], read A-frags ----
        // u32 index i in a row holds keys 2i, 2i+1: i = nt*8 + 2g + j -> key = nt*16+4g+2j+{0,1}
#pragma unroll
        for (int nt = 0; nt < 4; ++nt) {
            Pw[c * PSTRIDE + nt * 8 + 2 * g]     = pack_bf2(sv[nt][0], sv[nt][1]);
            Pw[c * PSTRIDE + nt * 8 + 2 * g + 1] = pack_bf2(sv[nt][2], sv[nt][3]);
        }
        asm volatile("s_waitcnt lgkmcnt(0)" ::: "memory");
        // read: A[m=c][k=ks2*32+8g+e] -> u32s at c*PSTRIDE + ks2*16 + 4g .. +3
        const bf16x8 pa0 = *reinterpret_cast<const bf16x8*>(&Pw[c * PSTRIDE + 4 * g]);
        const bf16x8 pa1 = *reinterpret_cast<const bf16x8*>(&Pw[c * PSTRIDE + 16 + 4 * g]);

        // ---- O += P V ----
#pragma unroll
        for (int ntd = 0; ntd < 4; ++ntd)
            acc[ntd] = __builtin_amdgcn_mfma_f32_16x16x32_bf16(pa0, vf[0][ntd], acc[ntd], 0, 0, 0);
#pragma unroll
        for (int ntd = 0; ntd < 4; ++ntd)
            acc[ntd] = __builtin_amdgcn_mfma_f32_16x16x32_bf16(pa1, vf[1][ntd], acc[ntd], 0, 0, 0);
    }

    // ---- finish: l across the 4 g-lanes of each q; write (m,l) + bf16 partial O ----
    float lf = l_run;
    lf += __shfl_xor(lf, 16);
    lf += __shfl_xor(lf, 32);

    const size_t pbase = (size_t)(b * NSPLIT + s) * 128 + qt;
    if (lane < 16) ml[pbase * 16 + c] = make_float2(m_run, lf);

    unsigned short* op = Opart + pbase * 1024;
#pragma unroll
    for (int r = 0; r < 4; ++r)
#pragma unroll
        for (int ntd = 0; ntd < 4; ++ntd)
            op[(4 * g + r) * 64 + ntd * 16 + c] = f2bf(acc[ntd][r]);
}

// ---------------- merge active splits ----------------
__global__ __launch_bounds__(64) void attn_merge(
    const float2* __restrict__ ml, const unsigned short* __restrict__ Opart,
    const int* __restrict__ VL, float* __restrict__ O)
{
    const int bid = blockIdx.x;
    const int b  = bid >> 7;
    const int qt = bid & 127;
    const int lane = threadIdx.x;
    const int q  = lane >> 2;
    const int d0 = (lane & 3) * 16;
    const int vlen = VL[b];
    const int nact = min(NSPLIT, (vlen + SPLIT_LEN - 1) / SPLIT_LEN);

    float M = -3.0e38f;
    float2 mls[NSPLIT];
    for (int s = 0; s < nact; ++s) {
        mls[s] = ml[((size_t)(b * NSPLIT + s) * 128 + qt) * 16 + q];
        M = fmaxf(M, mls[s].x);
    }
    float L = 0.f;
    float accv[16];
#pragma unroll
    for (int j = 0; j < 16; ++j) accv[j] = 0.f;

    for (int s = 0; s < nact; ++s) {
        const float w = fast_exp2((mls[s].x - M) * L2E);
        L += w * mls[s].y;
        const u16x8* src = reinterpret_cast<const u16x8*>(
            Opart + ((size_t)(b * NSPLIT + s) * 128 + qt) * 1024 + q * 64 + d0);
        const u16x8 lo = src[0], hi = src[1];
#pragma unroll
        for (int j = 0; j < 8; ++j) {
            accv[j]     += w * bf2f(lo[j]);
            accv[8 + j] += w * bf2f(hi[j]);
        }
    }
    const float inv = 1.0f / L;
    float* dst = O + ((size_t)(b * NQ + qt * 16 + q)) * DH + d0;
#pragma unroll
    for (int j = 0; j < 4; ++j) {
        float4 o;
        o.x = accv[4 * j]     * inv;
        o.y = accv[4 * j + 1] * inv;
        o.z = accv[4 * j + 2] * inv;
        o.w = accv[4 * j + 3] * inv;
        *reinterpret_cast<float4*>(dst + 4 * j) = o;
    }
}

// ---------------- round-1 fallback (direct fp32 loads), used only if ws too small ----------------
__global__ __launch_bounds__(64) void attn_fwd(
    const float* __restrict__ Q, const float* __restrict__ K,
    const float* __restrict__ V, const int* __restrict__ VL,
    float* __restrict__ O)
{
    __shared__ __align__(16) unsigned short Plds[16 * 40];
    const int bid = blockIdx.x;
    const int b  = bid >> 7;
    const int qt = bid & 127;
    const int q0 = qt * 16;
    const int lane = threadIdx.x;
    const int g = lane >> 4;
    const int c = lane & 15;
    const float* Qb = Q + ((size_t)b * NQ + q0) * DH;
    const float* Kb = K + (size_t)b * NK * DH;
    const float* Vb = V + (size_t)b * NK * DH;
    const int vlen = VL[b];
    bf16x8 qf[2];
#pragma unroll
    for (int ks = 0; ks < 2; ++ks) {
        const float* src = Qb + (size_t)c * DH + ks * 32 + g * 8;
#pragma unroll
        for (int e = 0; e < 8; ++e) qf[ks][e] = (short)f2bf(src[e] * 0.125f);
    }
    f32x4 acc[4];
#pragma unroll
    for (int nt = 0; nt < 4; ++nt) acc[nt] = (f32x4){0.f,0.f,0.f,0.f};
    float m_run[4], l_run[4];
#pragma unroll
    for (int r = 0; r < 4; ++r) { m_run[r] = -3.0e38f; l_run[r] = 0.f; }
    const int ntiles = (vlen + 31) / 32;
    for (int kt = 0; kt < ntiles; ++kt) {
        const int kv0 = kt * 32;
        f32x4 s[2] = {{0.f,0.f,0.f,0.f},{0.f,0.f,0.f,0.f}};
#pragma unroll
        for (int nt = 0; nt < 2; ++nt) {
            const float* kp = Kb + (size_t)(kv0 + nt * 16 + c) * DH + g * 8;
#pragma unroll
            for (int ks = 0; ks < 2; ++ks) {
                bf16x8 kf;
#pragma unroll
                for (int e = 0; e < 8; ++e) kf[e] = (short)f2bf(kp[ks * 32 + e]);
                s[nt] = __builtin_amdgcn_mfma_f32_16x16x32_bf16(qf[ks], kf, s[nt], 0, 0, 0);
            }
        }
        const bool msk0 = (kv0 + c)      >= vlen;
        const bool msk1 = (kv0 + 16 + c) >= vlen;
#pragma unroll
        for (int r = 0; r < 4; ++r) {
            if (msk0) s[0][r] = -1e30f;
            if (msk1) s[1][r] = -1e30f;
        }
        float tmax[4];
#pragma unroll
        for (int r = 0; r < 4; ++r) tmax[r] = fmaxf(s[0][r], s[1][r]);
#pragma unroll
        for (int mbit = 1; mbit < 16; mbit <<= 1)
#pragma unroll
            for (int r = 0; r < 4; ++r)
                tmax[r] = fmaxf(tmax[r], __shfl_xor(tmax[r], mbit));
        float p0[4], p1[4];
#pragma unroll
        for (int r = 0; r < 4; ++r) {
            const float mn = fmaxf(m_run[r], tmax[r]);
            const float sc = fast_exp2((m_run[r] - mn) * L2E);
            m_run[r] = mn;
            p0[r] = fast_exp2((s[0][r] - mn) * L2E);
            p1[r] = fast_exp2((s[1][r] - mn) * L2E);
            l_run[r] = l_run[r] * sc + p0[r] + p1[r];
#pragma unroll
            for (int nt = 0; nt < 4; ++nt) acc[nt][r] *= sc;
        }
#pragma unroll
        for (int r = 0; r < 4; ++r) {
            Plds[(4 * g + r) * 40 + c]      = f2bf(p0[r]);
            Plds[(4 * g + r) * 40 + 16 + c] = f2bf(p1[r]);
        }
        asm volatile("s_waitcnt lgkmcnt(0)" ::: "memory");
        const bf16x8 pa = *reinterpret_cast<const bf16x8*>(&Plds[c * 40 + g * 8]);
#pragma unroll
        for (int nt = 0; nt < 4; ++nt) {
            bf16x8 vf;
#pragma unroll
            for (int e = 0; e < 8; ++e)
                vf[e] = (short)f2bf(Vb[(size_t)(kv0 + 8 * g + e) * DH + nt * 16 + c]);
            acc[nt] = __builtin_amdgcn_mfma_f32_16x16x32_bf16(pa, vf, acc[nt], 0, 0, 0);
        }
    }
#pragma unroll
    for (int mbit = 1; mbit < 16; mbit <<= 1)
#pragma unroll
        for (int r = 0; r < 4; ++r)
            l_run[r] += __shfl_xor(l_run[r], mbit);
    float* Ob = O + ((size_t)b * NQ + q0) * DH;
#pragma unroll
    for (int r = 0; r < 4; ++r) {
        const float inv = 1.0f / l_run[r];
#pragma unroll
        for (int nt = 0; nt < 4; ++nt)
            Ob[(size_t)(4 * g + r) * DH + nt * 16 + c] = acc[nt][r] * inv;
    }
}

extern "C" void kernel_launch(void* const* d_in, const int* in_sizes, int n_in,
                              void* d_out, int out_size, void* d_ws, size_t ws_size,
                              hipStream_t stream) {
    const float* Q  = (const float*)d_in[0];
    const float* K  = (const float*)d_in[1];
    const float* V  = (const float*)d_in[2];
    const int*   VL = (const int*)d_in[3];
    float* O = (float*)d_out;

    // ws layout: Kbf 2MB | Vt 2MB | ml 1MB | Opart(bf16) 16MB  => NEED 21MB (R2 proved fits)
    const size_t KB_OFF = 0;
    const size_t VT_OFF = (size_t)2 << 20;
    const size_t ML_OFF = (size_t)4 << 20;
    const size_t OP_OFF = (size_t)5 << 20;
    const size_t NEED   = OP_OFF + (size_t)NB * NSPLIT * 128 * 1024 * 2;

    if (ws_size >= NEED) {
        char* w = (char*)d_ws;
        unsigned short* Kbf   = (unsigned short*)(w + KB_OFF);
        unsigned short* Vtp   = (unsigned short*)(w + VT_OFF);
        float2*         mlp   = (float2*)(w + ML_OFF);
        unsigned short* Opart = (unsigned short*)(w + OP_OFF);

        prep<<<768, 256, 0, stream>>>(K, V, Kbf, Vtp);
        attn_split<<<NB * NSPLIT * 32, 256, 0, stream>>>(Q, Kbf, Vtp, VL, mlp, Opart);
        attn_merge<<<NB * 128, 64, 0, stream>>>(mlp, Opart, VL, O);
    } else {
        attn_fwd<<<NB * 128, 64, 0, stream>>>(Q, K, V, VL, O);
    }
}

// Round 6
// 53.127 us; speedup vs baseline: 2.0943x; 1.3620x over previous
//
#include <hip/hip_runtime.h>
#include <hip/hip_bf16.h>

// DotProductAttention: B=8, Nq=2048, Nk=2048, D=64, fp32 in/out, per-batch key mask.
// Round 6: LDS-staged K/V chunks (global_load_lds w/ XOR swizzle), XCD-aware block
// swizzle, swapped QK^T lane-local softmax, split-KV x8, bf16 partials.

typedef __attribute__((ext_vector_type(8))) short bf16x8;
typedef __attribute__((ext_vector_type(8))) unsigned short u16x8;
typedef __attribute__((ext_vector_type(4))) float f32x4;

#define NQ 2048
#define NK 2048
#define DH 64
#define NB 8
#define NSPLIT 8
#define SPLIT_LEN 256
#define L2E 1.44269504088896341f
#define PSTRIDE 36   // u32 row stride for P repack tile (32 keypairs + 4 pad)

__device__ __forceinline__ unsigned short f2bf(float f) {
    union { float f; unsigned int u; } v; v.f = f;
    unsigned int u = v.u;
    u += 0x7FFFu + ((u >> 16) & 1u);   // RNE
    return (unsigned short)(u >> 16);
}
__device__ __forceinline__ float bf2f(unsigned short u) {
    union { unsigned int u; float f; } v; v.u = ((unsigned int)u) << 16; return v.f;
}
__device__ __forceinline__ unsigned int pack_bf2(float lo, float hi) {
    return ((unsigned int)f2bf(hi) << 16) | (unsigned int)f2bf(lo);
}
__device__ __forceinline__ float fast_exp2(float x) {
#if __has_builtin(__builtin_amdgcn_exp2f)
    return __builtin_amdgcn_exp2f(x);
#else
    return exp2f(x);
#endif
}
__device__ __forceinline__ void gload16(const void* g, void* l) {
    __builtin_amdgcn_global_load_lds(
        (const __attribute__((address_space(1))) void*)g,
        (__attribute__((address_space(3))) void*)l, 16, 0, 0);
}

// ---------------- fused prep: K->bf16 (blocks 0..511), V->Vt bf16 (blocks 512..767) ----------------
__global__ __launch_bounds__(256) void prep(const float* __restrict__ K,
                                            const float* __restrict__ V,
                                            unsigned short* __restrict__ Kbf,
                                            unsigned short* __restrict__ Vt) {
    if (blockIdx.x < 512) {
        const size_t idx = ((size_t)blockIdx.x * 256 + threadIdx.x) * 8;
        const float4 a = *reinterpret_cast<const float4*>(K + idx);
        const float4 b = *reinterpret_cast<const float4*>(K + idx + 4);
        bf16x8 o;
        o[0] = (short)f2bf(a.x); o[1] = (short)f2bf(a.y);
        o[2] = (short)f2bf(a.z); o[3] = (short)f2bf(a.w);
        o[4] = (short)f2bf(b.x); o[5] = (short)f2bf(b.y);
        o[6] = (short)f2bf(b.z); o[7] = (short)f2bf(b.w);
        *reinterpret_cast<bf16x8*>(Kbf + idx) = o;
    } else {
        __shared__ unsigned short T[64][65];
        const int bid2 = blockIdx.x - 512;
        const int b  = bid2 >> 5;
        const int k0 = (bid2 & 31) * 64;
        const int t  = threadIdx.x;
        const int r  = t >> 2;
        const int cb = (t & 3) * 16;
        const float* src = V + ((size_t)(b * NK + k0 + r)) * DH + cb;
#pragma unroll
        for (int j = 0; j < 16; ++j) T[r][cb + j] = f2bf(src[j]);
        __syncthreads();
        unsigned short* dstb = Vt + (size_t)b * DH * NK;
#pragma unroll
        for (int i = 0; i < 2; ++i) {
            const int cc = t + i * 256;
            const int d  = cc >> 3;
            const int kb = (cc & 7) * 8;
            bf16x8 o;
#pragma unroll
            for (int j = 0; j < 8; ++j) o[j] = (short)T[kb + j][d];
            *reinterpret_cast<bf16x8*>(dstb + (size_t)d * NK + k0 + kb) = o;
        }
    }
}

// ---------------- main: split-KV partials, LDS-staged K/V, swapped-QK^T ----------------
__global__ __launch_bounds__(256) void attn_split(
    const float* __restrict__ Q, const unsigned short* __restrict__ Kbf,
    const unsigned short* __restrict__ Vt, const int* __restrict__ VL,
    float2* __restrict__ ml, unsigned short* __restrict__ Opart)
{
    // KV[0,16K): K half-chunk [128 keys][64 d] bf16 (row 128B, XOR-swizzled)
    // KV[16K,32K): Vt half-chunk [64 d][128 keys] bf16 (row 256B, XOR-swizzled)
    __shared__ __align__(16) unsigned char KV[32768];
    __shared__ __align__(16) unsigned int Pl[4][16 * PSTRIDE];

    // XCD swizzle: bid = ((b+s)&7) + 8*(b*32+qg) -> all 32 blocks of (b,s) on one XCD
    const int bid = blockIdx.x;
    const int x  = bid & 7;
    const int t8 = bid >> 3;
    const int b  = t8 >> 5;
    const int qg = t8 & 31;
    const int s  = (x - b) & 7;

    const int vlen  = VL[b];
    const int kv_lo = s * SPLIT_LEN;
    if (kv_lo >= vlen) return;               // inactive split: merge skips it
    const int kv_hi = min(vlen, kv_lo + SPLIT_LEN);

    const int tid  = threadIdx.x;
    const int wv   = tid >> 6;
    const int lane = tid & 63;
    const int g = lane >> 4;                 // 0..3
    const int c = lane & 15;                 // 0..15
    const int qt = qg * 4 + wv;              // q-tile 0..127
    const int swl = (c & 7) << 4;            // read-side XOR (row&7)<<4, row&7 == c&7

    const float* Qb = Q + ((size_t)b * NQ + qt * 16) * DH;
    const unsigned char* Kc = (const unsigned char*)(Kbf + ((size_t)b * NK + kv_lo) * DH);
    const unsigned char* Vbase = (const unsigned char*)(Vt + (size_t)b * DH * NK);
    const int vk0b = kv_lo * 2;              // byte offset of chunk within a Vt row
    unsigned int* Pw = &Pl[wv][0];

    // Q B-frags: B[k = ks*32+g*8+e][n = c] = Q[q=c][d=k] * 0.125
    bf16x8 qf[2];
#pragma unroll
    for (int ks = 0; ks < 2; ++ks) {
        const float* src = Qb + (size_t)c * DH + ks * 32 + g * 8;
#pragma unroll
        for (int e = 0; e < 8; ++e) qf[ks][e] = (short)f2bf(src[e] * 0.125f);
    }

    f32x4 acc[4];                            // acc[ntd][r] = O[q=4g+r][d=ntd*16+c]
#pragma unroll
    for (int nt = 0; nt < 4; ++nt) acc[nt] = (f32x4){0.f, 0.f, 0.f, 0.f};
    float m_run = -3.0e38f, l_run = 0.f;     // per-lane: q = c

    const int nhalf = (kv_hi - kv_lo + 127) >> 7;   // 1 or 2 (block-uniform)
    for (int h = 0; h < nhalf; ++h) {
        if (h) __syncthreads();              // all waves done reading previous half

        // ---- stage K half: LDS_phys[p] = G[p ^ ((p>>7 &7)<<4)] (involution) ----
        {
            const unsigned char* Kh = Kc + h * (128 * 128);
#pragma unroll
            for (int i = 0; i < 4; ++i) {
                const int pb = wv * 4096 + i * 1024;     // wave-uniform LDS base
                const int p  = pb + lane * 16;
                const int sa = p ^ (((p >> 7) & 7) << 4);
                gload16(Kh + sa, KV + pb);
            }
            // ---- stage Vt half: rows d stride 4096B in global, 256B in LDS ----
#pragma unroll
            for (int i = 0; i < 4; ++i) {
                const int pb = wv * 4096 + i * 1024;
                const int p  = pb + lane * 16;
                const int a  = p ^ (((p >> 8) & 7) << 4);   // logical addr in V region
                const int d  = a >> 8;
                const int ko = a & 255;
                gload16(Vbase + (size_t)d * (NK * 2) + vk0b + h * 256 + ko,
                        KV + 16384 + pb);
            }
        }
        __syncthreads();                     // staging visible to all waves

        const int rem = kv_hi - kv_lo - h * 128;
        const int ntt = rem >= 64 ? 2 : 1;   // tiles in this half (block-uniform);
                                             // rem>128 clipped by loop guard below
        for (int tt = 0; tt < ntt; ++tt) {
            const int kb0 = h * 128 + tt * 64;
            if (kb0 >= kv_hi - kv_lo) break; // block-uniform
            const int kv0 = kv_lo + kb0;

            // ---- S^T: sv[nt][r] = S[q=c][key=kv0+nt*16+4g+r] ----
            f32x4 sv[4];
#pragma unroll
            for (int nt = 0; nt < 4; ++nt) {
                const int lh = tt * 64 + nt * 16 + c;        // local key in half
                const int aK = lh * 128 + g * 16;
                const bf16x8 kf0 = *reinterpret_cast<const bf16x8*>(KV + (aK ^ swl));
                const bf16x8 kf1 = *reinterpret_cast<const bf16x8*>(KV + ((aK + 64) ^ swl));
                f32x4 t = (f32x4){0.f, 0.f, 0.f, 0.f};
                t = __builtin_amdgcn_mfma_f32_16x16x32_bf16(kf0, qf[0], t, 0, 0, 0);
                t = __builtin_amdgcn_mfma_f32_16x16x32_bf16(kf1, qf[1], t, 0, 0, 0);
                sv[nt] = t;
            }

            // ---- V B-frags from LDS: vf[ks2][ntd] = V[key=tt*64+ks2*32+g*8+e][d=ntd*16+c] ----
            bf16x8 vf[2][4];
#pragma unroll
            for (int ks2 = 0; ks2 < 2; ++ks2)
#pragma unroll
                for (int ntd = 0; ntd < 4; ++ntd) {
                    const int aV = (ntd * 16 + c) * 256 + tt * 128 + ks2 * 64 + g * 16;
                    vf[ks2][ntd] = *reinterpret_cast<const bf16x8*>(KV + 16384 + (aV ^ swl));
                }

            // ---- mask key >= vlen (last tile only) ----
            if (kv0 + 64 > kv_hi) {
#pragma unroll
                for (int nt = 0; nt < 4; ++nt)
#pragma unroll
                    for (int r = 0; r < 4; ++r)
                        if (kv0 + nt * 16 + 4 * g + r >= vlen) sv[nt][r] = -1e30f;
            }

            // ---- row max: 15 local fmax + 2 cross-group shuffles ----
            float tmax = fmaxf(fmaxf(fmaxf(sv[0][0], sv[0][1]), fmaxf(sv[0][2], sv[0][3])),
                               fmaxf(fmaxf(sv[1][0], sv[1][1]), fmaxf(sv[1][2], sv[1][3])));
            tmax = fmaxf(tmax, fmaxf(fmaxf(fmaxf(sv[2][0], sv[2][1]), fmaxf(sv[2][2], sv[2][3])),
                                     fmaxf(fmaxf(sv[3][0], sv[3][1]), fmaxf(sv[3][2], sv[3][3]))));
            tmax = fmaxf(tmax, __shfl_xor(tmax, 16));
            tmax = fmaxf(tmax, __shfl_xor(tmax, 32));

            const float mn = fmaxf(m_run, tmax);
            const float sc = fast_exp2((m_run - mn) * L2E);
            m_run = mn;

            float rs = 0.f;
#pragma unroll
            for (int nt = 0; nt < 4; ++nt)
#pragma unroll
                for (int r = 0; r < 4; ++r) {
                    const float p = fast_exp2((sv[nt][r] - mn) * L2E);
                    sv[nt][r] = p;
                    rs += p;
                }
            l_run = l_run * sc + rs;

            // ---- rescale O: sc for q=4g+r pulled from lane 4g+r ----
            float scq[4];
#pragma unroll
            for (int r = 0; r < 4; ++r)
                scq[r] = __int_as_float(__builtin_amdgcn_ds_bpermute((4 * g + r) * 4,
                                                                     __float_as_int(sc)));
#pragma unroll
            for (int ntd = 0; ntd < 4; ++ntd)
#pragma unroll
                for (int r = 0; r < 4; ++r) acc[ntd][r] *= scq[r];

            // ---- P repack via per-wave LDS tile ----
#pragma unroll
            for (int nt = 0; nt < 4; ++nt) {
                Pw[c * PSTRIDE + nt * 8 + 2 * g]     = pack_bf2(sv[nt][0], sv[nt][1]);
                Pw[c * PSTRIDE + nt * 8 + 2 * g + 1] = pack_bf2(sv[nt][2], sv[nt][3]);
            }
            asm volatile("s_waitcnt lgkmcnt(0)" ::: "memory");
            const bf16x8 pa0 = *reinterpret_cast<const bf16x8*>(&Pw[c * PSTRIDE + 4 * g]);
            const bf16x8 pa1 = *reinterpret_cast<const bf16x8*>(&Pw[c * PSTRIDE + 16 + 4 * g]);

            // ---- O += P V ----
#pragma unroll
            for (int ntd = 0; ntd < 4; ++ntd)
                acc[ntd] = __builtin_amdgcn_mfma_f32_16x16x32_bf16(pa0, vf[0][ntd], acc[ntd], 0, 0, 0);
#pragma unroll
            for (int ntd = 0; ntd < 4; ++ntd)
                acc[ntd] = __builtin_amdgcn_mfma_f32_16x16x32_bf16(pa1, vf[1][ntd], acc[ntd], 0, 0, 0);
        }
    }

    // ---- finish: l across g-groups; write (m,l) + bf16 partial O ----
    float lf = l_run;
    lf += __shfl_xor(lf, 16);
    lf += __shfl_xor(lf, 32);

    const size_t pbase = (size_t)(b * NSPLIT + s) * 128 + qt;
    if (lane < 16) ml[pbase * 16 + c] = make_float2(m_run, lf);

    unsigned short* op = Opart + pbase * 1024;
#pragma unroll
    for (int r = 0; r < 4; ++r)
#pragma unroll
        for (int ntd = 0; ntd < 4; ++ntd)
            op[(4 * g + r) * 64 + ntd * 16 + c] = f2bf(acc[ntd][r]);
}

// ---------------- merge active splits ----------------
__global__ __launch_bounds__(64) void attn_merge(
    const float2* __restrict__ ml, const unsigned short* __restrict__ Opart,
    const int* __restrict__ VL, float* __restrict__ O)
{
    const int bid = blockIdx.x;
    const int b  = bid >> 7;
    const int qt = bid & 127;
    const int lane = threadIdx.x;
    const int q  = lane >> 2;
    const int d0 = (lane & 3) * 16;
    const int vlen = VL[b];
    const int nact = min(NSPLIT, (vlen + SPLIT_LEN - 1) / SPLIT_LEN);

    float M = -3.0e38f;
    float2 mls[NSPLIT];
    for (int s = 0; s < nact; ++s) {
        mls[s] = ml[((size_t)(b * NSPLIT + s) * 128 + qt) * 16 + q];
        M = fmaxf(M, mls[s].x);
    }
    float L = 0.f;
    float accv[16];
#pragma unroll
    for (int j = 0; j < 16; ++j) accv[j] = 0.f;

    for (int s = 0; s < nact; ++s) {
        const float w = fast_exp2((mls[s].x - M) * L2E);
        L += w * mls[s].y;
        const u16x8* src = reinterpret_cast<const u16x8*>(
            Opart + ((size_t)(b * NSPLIT + s) * 128 + qt) * 1024 + q * 64 + d0);
        const u16x8 lo = src[0], hi = src[1];
#pragma unroll
        for (int j = 0; j < 8; ++j) {
            accv[j]     += w * bf2f(lo[j]);
            accv[8 + j] += w * bf2f(hi[j]);
        }
    }
    const float inv = 1.0f / L;
    float* dst = O + ((size_t)(b * NQ + qt * 16 + q)) * DH + d0;
#pragma unroll
    for (int j = 0; j < 4; ++j) {
        float4 o;
        o.x = accv[4 * j]     * inv;
        o.y = accv[4 * j + 1] * inv;
        o.z = accv[4 * j + 2] * inv;
        o.w = accv[4 * j + 3] * inv;
        *reinterpret_cast<float4*>(dst + 4 * j) = o;
    }
}

// ---------------- round-1 fallback (direct fp32 loads), used only if ws too small ----------------
__global__ __launch_bounds__(64) void attn_fwd(
    const float* __restrict__ Q, const float* __restrict__ K,
    const float* __restrict__ V, const int* __restrict__ VL,
    float* __restrict__ O)
{
    __shared__ __align__(16) unsigned short Plds[16 * 40];
    const int bid = blockIdx.x;
    const int b  = bid >> 7;
    const int qt = bid & 127;
    const int q0 = qt * 16;
    const int lane = threadIdx.x;
    const int g = lane >> 4;
    const int c = lane & 15;
    const float* Qb = Q + ((size_t)b * NQ + q0) * DH;
    const float* Kb = K + (size_t)b * NK * DH;
    const float* Vb = V + (size_t)b * NK * DH;
    const int vlen = VL[b];
    bf16x8 qf[2];
#pragma unroll
    for (int ks = 0; ks < 2; ++ks) {
        const float* src = Qb + (size_t)c * DH + ks * 32 + g * 8;
#pragma unroll
        for (int e = 0; e < 8; ++e) qf[ks][e] = (short)f2bf(src[e] * 0.125f);
    }
    f32x4 acc[4];
#pragma unroll
    for (int nt = 0; nt < 4; ++nt) acc[nt] = (f32x4){0.f,0.f,0.f,0.f};
    float m_run[4], l_run[4];
#pragma unroll
    for (int r = 0; r < 4; ++r) { m_run[r] = -3.0e38f; l_run[r] = 0.f; }
    const int ntiles = (vlen + 31) / 32;
    for (int kt = 0; kt < ntiles; ++kt) {
        const int kv0 = kt * 32;
        f32x4 s[2] = {{0.f,0.f,0.f,0.f},{0.f,0.f,0.f,0.f}};
#pragma unroll
        for (int nt = 0; nt < 2; ++nt) {
            const float* kp = Kb + (size_t)(kv0 + nt * 16 + c) * DH + g * 8;
#pragma unroll
            for (int ks = 0; ks < 2; ++ks) {
                bf16x8 kf;
#pragma unroll
                for (int e = 0; e < 8; ++e) kf[e] = (short)f2bf(kp[ks * 32 + e]);
                s[nt] = __builtin_amdgcn_mfma_f32_16x16x32_bf16(qf[ks], kf, s[nt], 0, 0, 0);
            }
        }
        const bool msk0 = (kv0 + c)      >= vlen;
        const bool msk1 = (kv0 + 16 + c) >= vlen;
#pragma unroll
        for (int r = 0; r < 4; ++r) {
            if (msk0) s[0][r] = -1e30f;
            if (msk1) s[1][r] = -1e30f;
        }
        float tmax[4];
#pragma unroll
        for (int r = 0; r < 4; ++r) tmax[r] = fmaxf(s[0][r], s[1][r]);
#pragma unroll
        for (int mbit = 1; mbit < 16; mbit <<= 1)
#pragma unroll
            for (int r = 0; r < 4; ++r)
                tmax[r] = fmaxf(tmax[r], __shfl_xor(tmax[r], mbit));
        float p0[4], p1[4];
#pragma unroll
        for (int r = 0; r < 4; ++r) {
            const float mn = fmaxf(m_run[r], tmax[r]);
            const float sc = fast_exp2((m_run[r] - mn) * L2E);
            m_run[r] = mn;
            p0[r] = fast_exp2((s[0][r] - mn) * L2E);
            p1[r] = fast_exp2((s[1][r] - mn) * L2E);
            l_run[r] = l_run[r] * sc + p0[r] + p1[r];
#pragma unroll
            for (int nt = 0; nt < 4; ++nt) acc[nt][r] *= sc;
        }
#pragma unroll
        for (int r = 0; r < 4; ++r) {
            Plds[(4 * g + r) * 40 + c]      = f2bf(p0[r]);
            Plds[(4 * g + r) * 40 + 16 + c] = f2bf(p1[r]);
        }
        asm volatile("s_waitcnt lgkmcnt(0)" ::: "memory");
        const bf16x8 pa = *reinterpret_cast<const bf16x8*>(&Plds[c * 40 + g * 8]);
#pragma unroll
        for (int nt = 0; nt < 4; ++nt) {
            bf16x8 vf;
#pragma unroll
            for (int e = 0; e < 8; ++e)
                vf[e] = (short)f2bf(Vb[(size_t)(kv0 + 8 * g + e) * DH + nt * 16 + c]);
            acc[nt] = __builtin_amdgcn_mfma_f32_16x16x32_bf16(pa, vf, acc[nt], 0, 0, 0);
        }
    }
#pragma unroll
    for (int mbit = 1; mbit < 16; mbit <<= 1)
#pragma unroll
        for (int r = 0; r < 4; ++r)
            l_run[r] += __shfl_xor(l_run[r], mbit);
    float* Ob = O + ((size_t)b * NQ + q0) * DH;
#pragma unroll
    for (int r = 0; r < 4; ++r) {
        const float inv = 1.0f / l_run[r];
#pragma unroll
        for (int nt = 0; nt < 4; ++nt)
            Ob[(size_t)(4 * g + r) * DH + nt * 16 + c] = acc[nt][r] * inv;
    }
}

extern "C" void kernel_launch(void* const* d_in, const int* in_sizes, int n_in,
                              void* d_out, int out_size, void* d_ws, size_t ws_size,
                              hipStream_t stream) {
    const float* Q  = (const float*)d_in[0];
    const float* K  = (const float*)d_in[1];
    const float* V  = (const float*)d_in[2];
    const int*   VL = (const int*)d_in[3];
    float* O = (float*)d_out;

    // ws layout: Kbf 2MB | Vt 2MB | ml 1MB | Opart(bf16) 16MB  => NEED 21MB (proven fits)
    const size_t KB_OFF = 0;
    const size_t VT_OFF = (size_t)2 << 20;
    const size_t ML_OFF = (size_t)4 << 20;
    const size_t OP_OFF = (size_t)5 << 20;
    const size_t NEED   = OP_OFF + (size_t)NB * NSPLIT * 128 * 1024 * 2;

    if (ws_size >= NEED) {
        char* w = (char*)d_ws;
        unsigned short* Kbf   = (unsigned short*)(w + KB_OFF);
        unsigned short* Vtp   = (unsigned short*)(w + VT_OFF);
        float2*         mlp   = (float2*)(w + ML_OFF);
        unsigned short* Opart = (unsigned short*)(w + OP_OFF);

        prep<<<768, 256, 0, stream>>>(K, V, Kbf, Vtp);
        attn_split<<<NB * NSPLIT * 32, 256, 0, stream>>>(Q, Kbf, Vtp, VL, mlp, Opart);
        attn_merge<<<NB * 128, 64, 0, stream>>>(mlp, Opart, VL, O);
    } else {
        attn_fwd<<<NB * 128, 64, 0, stream>>>(Q, K, V, VL, O);
    }
}

// Round 7
// 50.411 us; speedup vs baseline: 2.2071x; 1.0539x over previous
//
#include <hip/hip_runtime.h>
#include <hip/hip_bf16.h>

// DotProductAttention: B=8, Nq=2048, Nk=2048, D=64, fp32 in/out, per-batch key mask.
// Round 7: double-buffered quarter staging with counted vmcnt (2-phase pipeline),
// LDS-staged K/V, XCD swizzle, swapped QK^T lane-local softmax, split-KV x8.

typedef __attribute__((ext_vector_type(8))) short bf16x8;
typedef __attribute__((ext_vector_type(8))) unsigned short u16x8;
typedef __attribute__((ext_vector_type(4))) float f32x4;

#define NQ 2048
#define NK 2048
#define DH 64
#define NB 8
#define NSPLIT 8
#define SPLIT_LEN 256
#define L2E 1.44269504088896341f
#define PSTRIDE 36   // u32 row stride for P repack tile (32 keypairs + 4 pad)

#define VMCNT(n) asm volatile("s_waitcnt vmcnt(" #n ")" ::: "memory")

__device__ __forceinline__ unsigned short f2bf(float f) {
    union { float f; unsigned int u; } v; v.f = f;
    unsigned int u = v.u;
    u += 0x7FFFu + ((u >> 16) & 1u);   // RNE
    return (unsigned short)(u >> 16);
}
__device__ __forceinline__ float bf2f(unsigned short u) {
    union { unsigned int u; float f; } v; v.u = ((unsigned int)u) << 16; return v.f;
}
__device__ __forceinline__ unsigned int pack_bf2(float lo, float hi) {
    return ((unsigned int)f2bf(hi) << 16) | (unsigned int)f2bf(lo);
}
__device__ __forceinline__ float fast_exp2(float x) {
#if __has_builtin(__builtin_amdgcn_exp2f)
    return __builtin_amdgcn_exp2f(x);
#else
    return exp2f(x);
#endif
}
__device__ __forceinline__ void gload16(const void* g, void* l) {
    __builtin_amdgcn_global_load_lds(
        (const __attribute__((address_space(1))) void*)g,
        (__attribute__((address_space(3))) void*)l, 16, 0, 0);
}

// ---------------- fused prep: K->bf16 (blocks 0..511), V->Vt bf16 (blocks 512..767) ----------------
__global__ __launch_bounds__(256) void prep(const float* __restrict__ K,
                                            const float* __restrict__ V,
                                            unsigned short* __restrict__ Kbf,
                                            unsigned short* __restrict__ Vt) {
    if (blockIdx.x < 512) {
        const size_t idx = ((size_t)blockIdx.x * 256 + threadIdx.x) * 8;
        const float4 a = *reinterpret_cast<const float4*>(K + idx);
        const float4 b = *reinterpret_cast<const float4*>(K + idx + 4);
        bf16x8 o;
        o[0] = (short)f2bf(a.x); o[1] = (short)f2bf(a.y);
        o[2] = (short)f2bf(a.z); o[3] = (short)f2bf(a.w);
        o[4] = (short)f2bf(b.x); o[5] = (short)f2bf(b.y);
        o[6] = (short)f2bf(b.z); o[7] = (short)f2bf(b.w);
        *reinterpret_cast<bf16x8*>(Kbf + idx) = o;
    } else {
        __shared__ unsigned short T[64][65];
        const int bid2 = blockIdx.x - 512;
        const int b  = bid2 >> 5;
        const int k0 = (bid2 & 31) * 64;
        const int t  = threadIdx.x;
        const int r  = t >> 2;
        const int cb = (t & 3) * 16;
        const float* src = V + ((size_t)(b * NK + k0 + r)) * DH + cb;
#pragma unroll
        for (int j4 = 0; j4 < 4; ++j4) {
            const float4 v = *reinterpret_cast<const float4*>(src + j4 * 4);
            T[r][cb + j4 * 4 + 0] = f2bf(v.x);
            T[r][cb + j4 * 4 + 1] = f2bf(v.y);
            T[r][cb + j4 * 4 + 2] = f2bf(v.z);
            T[r][cb + j4 * 4 + 3] = f2bf(v.w);
        }
        __syncthreads();
        unsigned short* dstb = Vt + (size_t)b * DH * NK;
#pragma unroll
        for (int i = 0; i < 2; ++i) {
            const int cc = t + i * 256;
            const int d  = cc >> 3;
            const int kb = (cc & 7) * 8;
            bf16x8 o;
#pragma unroll
            for (int j = 0; j < 8; ++j) o[j] = (short)T[kb + j][d];
            *reinterpret_cast<bf16x8*>(dstb + (size_t)d * NK + k0 + kb) = o;
        }
    }
}

// ---------------- main: split-KV partials, dbuf LDS staging, swapped-QK^T ----------------
__global__ __launch_bounds__(256) void attn_split(
    const float* __restrict__ Q, const unsigned short* __restrict__ Kbf,
    const unsigned short* __restrict__ Vt, const int* __restrict__ VL,
    float2* __restrict__ ml, unsigned short* __restrict__ Opart)
{
    // 2 buffers x (K quarter 8KB [64 keys][128B row] + V quarter 8KB [64 d][128B row]),
    // both XOR-swizzled: phys = logical ^ (((logical>>7)&7)<<4)
    __shared__ __align__(16) unsigned char KV[32768];
    __shared__ __align__(16) unsigned int Pl[4][16 * PSTRIDE];

    // XCD swizzle: all 32 blocks of one (b,s) chunk land on one XCD
    const int bid = blockIdx.x;
    const int x  = bid & 7;
    const int t8 = bid >> 3;
    const int b  = t8 >> 5;
    const int qg = t8 & 31;
    const int s  = (x - b) & 7;

    const int vlen  = VL[b];
    const int kv_lo = s * SPLIT_LEN;
    if (kv_lo >= vlen) return;               // inactive split: merge skips it
    const int kv_hi = min(vlen, kv_lo + SPLIT_LEN);
    const int chunk = kv_hi - kv_lo;
    const int nt    = (chunk + 63) >> 6;     // 1..4 quarters (block-uniform)

    const int tid  = threadIdx.x;
    const int wv   = tid >> 6;
    const int lane = tid & 63;
    const int g = lane >> 4;                 // 0..3
    const int c = lane & 15;                 // 0..15
    const int qt = qg * 4 + wv;              // q-tile 0..127
    const int swl = (c & 7) << 4;            // read-side XOR ((row&7)<<4), row&7 == c&7

    const float* Qb = Q + ((size_t)b * NQ + qt * 16) * DH;
    const unsigned char* Kc = (const unsigned char*)(Kbf + ((size_t)b * NK + kv_lo) * DH);
    const unsigned char* Vbase = (const unsigned char*)(Vt + (size_t)b * DH * NK);
    const int vk0b = kv_lo * 2;              // byte offset of chunk within a Vt row
    unsigned int* Pw = &Pl[wv][0];

    // Q B-frags: B[k = ks*32+g*8+e][n = c] = Q[q=c][d=k] * 0.125
    bf16x8 qf[2];
#pragma unroll
    for (int ks = 0; ks < 2; ++ks) {
        const float* src = Qb + (size_t)c * DH + ks * 32 + g * 8;
#pragma unroll
        for (int e = 0; e < 8; ++e) qf[ks][e] = (short)f2bf(src[e] * 0.125f);
    }

    f32x4 acc[4];                            // acc[ntd][r] = O[q=4g+r][d=ntd*16+c]
#pragma unroll
    for (int i = 0; i < 4; ++i) acc[i] = (f32x4){0.f, 0.f, 0.f, 0.f};
    float m_run = -3.0e38f, l_run = 0.f;     // per-lane: q = c

    // ---- staging: 4 gload16 per wave per quarter (2 K + 2 V) ----
    auto stage = [&](int t) {
        const int buf = (t & 1) << 14;       // 0 / 16384
        const unsigned char* Ks = Kc + t * 8192;    // K quarter is contiguous 8KB
#pragma unroll
        for (int i = 0; i < 2; ++i) {
            const int off = wv * 2048 + i * 1024 + lane * 16;          // 0..8191
            const int sw  = off ^ (((off >> 7) & 7) << 4);             // involution
            gload16(Ks + sw, KV + buf + wv * 2048 + i * 1024);
        }
#pragma unroll
        for (int i = 0; i < 2; ++i) {
            const int off = wv * 2048 + i * 1024 + lane * 16;
            const int a   = off ^ (((off >> 7) & 7) << 4);
            const int d   = a >> 7;
            const int ko  = a & 127;
            gload16(Vbase + (size_t)d * (NK * 2) + vk0b + t * 128 + ko,
                    KV + buf + 8192 + wv * 2048 + i * 1024);
        }
    };

    stage(0);                                // prologue prefetch

    for (int t = 0; t < nt; ++t) {
        if (t + 1 < nt) {
            stage(t + 1);                    // buf[(t+1)&1] free: end-barrier of t-1 passed
            VMCNT(4);                        // wait stage(t) only; stage(t+1) stays in flight
        } else {
            VMCNT(0);
        }
        __builtin_amdgcn_s_barrier();        // stage(t) visible to all waves
        __builtin_amdgcn_sched_barrier(0);

        const int buf = (t & 1) << 14;
        const unsigned char* Kr = KV + buf;
        const unsigned char* Vr = KV + buf + 8192;
        const int kv0 = kv_lo + (t << 6);

        // ---- S^T: sv[nt4][r] = S[q=c][key=kv0+nt4*16+4g+r] ----
        f32x4 sv[4];
#pragma unroll
        for (int nt4 = 0; nt4 < 4; ++nt4) {
            const int aK = (nt4 * 16 + c) * 128 + g * 16;
            const bf16x8 kf0 = *reinterpret_cast<const bf16x8*>(Kr + (aK ^ swl));
            const bf16x8 kf1 = *reinterpret_cast<const bf16x8*>(Kr + ((aK + 64) ^ swl));
            f32x4 tacc = (f32x4){0.f, 0.f, 0.f, 0.f};
            tacc = __builtin_amdgcn_mfma_f32_16x16x32_bf16(kf0, qf[0], tacc, 0, 0, 0);
            tacc = __builtin_amdgcn_mfma_f32_16x16x32_bf16(kf1, qf[1], tacc, 0, 0, 0);
            sv[nt4] = tacc;
        }

        // ---- V B-frags: vf[ks2][ntd] = V[key=ks2*32+g*8+e][d=ntd*16+c] ----
        bf16x8 vf[2][4];
#pragma unroll
        for (int ks2 = 0; ks2 < 2; ++ks2)
#pragma unroll
            for (int ntd = 0; ntd < 4; ++ntd) {
                const int aV = (ntd * 16 + c) * 128 + ks2 * 64 + g * 16;
                vf[ks2][ntd] = *reinterpret_cast<const bf16x8*>(Vr + (aV ^ swl));
            }

        // ---- mask key >= vlen (last quarter only) ----
        if (kv0 + 64 > kv_hi) {
#pragma unroll
            for (int nt4 = 0; nt4 < 4; ++nt4)
#pragma unroll
                for (int r = 0; r < 4; ++r)
                    if (kv0 + nt4 * 16 + 4 * g + r >= vlen) sv[nt4][r] = -1e30f;
        }

        // ---- row max: 15 local fmax + 2 cross-group shuffles ----
        float tmax = fmaxf(fmaxf(fmaxf(sv[0][0], sv[0][1]), fmaxf(sv[0][2], sv[0][3])),
                           fmaxf(fmaxf(sv[1][0], sv[1][1]), fmaxf(sv[1][2], sv[1][3])));
        tmax = fmaxf(tmax, fmaxf(fmaxf(fmaxf(sv[2][0], sv[2][1]), fmaxf(sv[2][2], sv[2][3])),
                                 fmaxf(fmaxf(sv[3][0], sv[3][1]), fmaxf(sv[3][2], sv[3][3]))));
        tmax = fmaxf(tmax, __shfl_xor(tmax, 16));
        tmax = fmaxf(tmax, __shfl_xor(tmax, 32));

        const float mn = fmaxf(m_run, tmax);
        const float sc = fast_exp2((m_run - mn) * L2E);
        m_run = mn;

        float rs = 0.f;
#pragma unroll
        for (int nt4 = 0; nt4 < 4; ++nt4)
#pragma unroll
            for (int r = 0; r < 4; ++r) {
                const float p = fast_exp2((sv[nt4][r] - mn) * L2E);
                sv[nt4][r] = p;
                rs += p;
            }
        l_run = l_run * sc + rs;

        // ---- rescale O: sc for q=4g+r pulled from lane 4g+r ----
        float scq[4];
#pragma unroll
        for (int r = 0; r < 4; ++r)
            scq[r] = __int_as_float(__builtin_amdgcn_ds_bpermute((4 * g + r) * 4,
                                                                 __float_as_int(sc)));
#pragma unroll
        for (int ntd = 0; ntd < 4; ++ntd)
#pragma unroll
            for (int r = 0; r < 4; ++r) acc[ntd][r] *= scq[r];

        // ---- P repack via per-wave LDS tile ----
#pragma unroll
        for (int nt4 = 0; nt4 < 4; ++nt4) {
            Pw[c * PSTRIDE + nt4 * 8 + 2 * g]     = pack_bf2(sv[nt4][0], sv[nt4][1]);
            Pw[c * PSTRIDE + nt4 * 8 + 2 * g + 1] = pack_bf2(sv[nt4][2], sv[nt4][3]);
        }
        asm volatile("s_waitcnt lgkmcnt(0)" ::: "memory");
        const bf16x8 pa0 = *reinterpret_cast<const bf16x8*>(&Pw[c * PSTRIDE + 4 * g]);
        const bf16x8 pa1 = *reinterpret_cast<const bf16x8*>(&Pw[c * PSTRIDE + 16 + 4 * g]);

        // ---- O += P V ----
#pragma unroll
        for (int ntd = 0; ntd < 4; ++ntd)
            acc[ntd] = __builtin_amdgcn_mfma_f32_16x16x32_bf16(pa0, vf[0][ntd], acc[ntd], 0, 0, 0);
#pragma unroll
        for (int ntd = 0; ntd < 4; ++ntd)
            acc[ntd] = __builtin_amdgcn_mfma_f32_16x16x32_bf16(pa1, vf[1][ntd], acc[ntd], 0, 0, 0);

        if (t + 1 < nt) {                    // all waves done reading buf[t&1]
            __builtin_amdgcn_sched_barrier(0);
            __builtin_amdgcn_s_barrier();
        }
    }

    // ---- finish: l across g-groups; write (m,l) + bf16 partial O ----
    float lf = l_run;
    lf += __shfl_xor(lf, 16);
    lf += __shfl_xor(lf, 32);

    const size_t pbase = (size_t)(b * NSPLIT + s) * 128 + qt;
    if (lane < 16) ml[pbase * 16 + c] = make_float2(m_run, lf);

    unsigned short* op = Opart + pbase * 1024;
#pragma unroll
    for (int r = 0; r < 4; ++r)
#pragma unroll
        for (int ntd = 0; ntd < 4; ++ntd)
            op[(4 * g + r) * 64 + ntd * 16 + c] = f2bf(acc[ntd][r]);
}

// ---------------- merge active splits ----------------
__global__ __launch_bounds__(64) void attn_merge(
    const float2* __restrict__ ml, const unsigned short* __restrict__ Opart,
    const int* __restrict__ VL, float* __restrict__ O)
{
    const int bid = blockIdx.x;
    const int b  = bid >> 7;
    const int qt = bid & 127;
    const int lane = threadIdx.x;
    const int q  = lane >> 2;
    const int d0 = (lane & 3) * 16;
    const int vlen = VL[b];
    const int nact = min(NSPLIT, (vlen + SPLIT_LEN - 1) / SPLIT_LEN);

    float M = -3.0e38f;
    float2 mls[NSPLIT];
    for (int s = 0; s < nact; ++s) {
        mls[s] = ml[((size_t)(b * NSPLIT + s) * 128 + qt) * 16 + q];
        M = fmaxf(M, mls[s].x);
    }
    float L = 0.f;
    float accv[16];
#pragma unroll
    for (int j = 0; j < 16; ++j) accv[j] = 0.f;

    for (int s = 0; s < nact; ++s) {
        const float w = fast_exp2((mls[s].x - M) * L2E);
        L += w * mls[s].y;
        const u16x8* src = reinterpret_cast<const u16x8*>(
            Opart + ((size_t)(b * NSPLIT + s) * 128 + qt) * 1024 + q * 64 + d0);
        const u16x8 lo = src[0], hi = src[1];
#pragma unroll
        for (int j = 0; j < 8; ++j) {
            accv[j]     += w * bf2f(lo[j]);
            accv[8 + j] += w * bf2f(hi[j]);
        }
    }
    const float inv = 1.0f / L;
    float* dst = O + ((size_t)(b * NQ + qt * 16 + q)) * DH + d0;
#pragma unroll
    for (int j = 0; j < 4; ++j) {
        float4 o;
        o.x = accv[4 * j]     * inv;
        o.y = accv[4 * j + 1] * inv;
        o.z = accv[4 * j + 2] * inv;
        o.w = accv[4 * j + 3] * inv;
        *reinterpret_cast<float4*>(dst + 4 * j) = o;
    }
}

// ---------------- round-1 fallback (direct fp32 loads), used only if ws too small ----------------
__global__ __launch_bounds__(64) void attn_fwd(
    const float* __restrict__ Q, const float* __restrict__ K,
    const float* __restrict__ V, const int* __restrict__ VL,
    float* __restrict__ O)
{
    __shared__ __align__(16) unsigned short Plds[16 * 40];
    const int bid = blockIdx.x;
    const int b  = bid >> 7;
    const int qt = bid & 127;
    const int q0 = qt * 16;
    const int lane = threadIdx.x;
    const int g = lane >> 4;
    const int c = lane & 15;
    const float* Qb = Q + ((size_t)b * NQ + q0) * DH;
    const float* Kb = K + (size_t)b * NK * DH;
    const float* Vb = V + (size_t)b * NK * DH;
    const int vlen = VL[b];
    bf16x8 qf[2];
#pragma unroll
    for (int ks = 0; ks < 2; ++ks) {
        const float* src = Qb + (size_t)c * DH + ks * 32 + g * 8;
#pragma unroll
        for (int e = 0; e < 8; ++e) qf[ks][e] = (short)f2bf(src[e] * 0.125f);
    }
    f32x4 acc[4];
#pragma unroll
    for (int nt = 0; nt < 4; ++nt) acc[nt] = (f32x4){0.f,0.f,0.f,0.f};
    float m_run[4], l_run[4];
#pragma unroll
    for (int r = 0; r < 4; ++r) { m_run[r] = -3.0e38f; l_run[r] = 0.f; }
    const int ntiles = (vlen + 31) / 32;
    for (int kt = 0; kt < ntiles; ++kt) {
        const int kv0 = kt * 32;
        f32x4 s[2] = {{0.f,0.f,0.f,0.f},{0.f,0.f,0.f,0.f}};
#pragma unroll
        for (int nt = 0; nt < 2; ++nt) {
            const float* kp = Kb + (size_t)(kv0 + nt * 16 + c) * DH + g * 8;
#pragma unroll
            for (int ks = 0; ks < 2; ++ks) {
                bf16x8 kf;
#pragma unroll
                for (int e = 0; e < 8; ++e) kf[e] = (short)f2bf(kp[ks * 32 + e]);
                s[nt] = __builtin_amdgcn_mfma_f32_16x16x32_bf16(qf[ks], kf, s[nt], 0, 0, 0);
            }
        }
        const bool msk0 = (kv0 + c)      >= vlen;
        const bool msk1 = (kv0 + 16 + c) >= vlen;
#pragma unroll
        for (int r = 0; r < 4; ++r) {
            if (msk0) s[0][r] = -1e30f;
            if (msk1) s[1][r] = -1e30f;
        }
        float tmax[4];
#pragma unroll
        for (int r = 0; r < 4; ++r) tmax[r] = fmaxf(s[0][r], s[1][r]);
#pragma unroll
        for (int mbit = 1; mbit < 16; mbit <<= 1)
#pragma unroll
            for (int r = 0; r < 4; ++r)
                tmax[r] = fmaxf(tmax[r], __shfl_xor(tmax[r], mbit));
        float p0[4], p1[4];
#pragma unroll
        for (int r = 0; r < 4; ++r) {
            const float mn = fmaxf(m_run[r], tmax[r]);
            const float sc = fast_exp2((m_run[r] - mn) * L2E);
            m_run[r] = mn;
            p0[r] = fast_exp2((s[0][r] - mn) * L2E);
            p1[r] = fast_exp2((s[1][r] - mn) * L2E);
            l_run[r] = l_run[r] * sc + p0[r] + p1[r];
#pragma unroll
            for (int nt = 0; nt < 4; ++nt) acc[nt][r] *= sc;
        }
#pragma unroll
        for (int r = 0; r < 4; ++r) {
            Plds[(4 * g + r) * 40 + c]      = f2bf(p0[r]);
            Plds[(4 * g + r) * 40 + 16 + c] = f2bf(p1[r]);
        }
        asm volatile("s_waitcnt lgkmcnt(0)" ::: "memory");
        const bf16x8 pa = *reinterpret_cast<const bf16x8*>(&Plds[c * 40 + g * 8]);
#pragma unroll
        for (int nt = 0; nt < 4; ++nt) {
            bf16x8 vf;
#pragma unroll
            for (int e = 0; e < 8; ++e)
                vf[e] = (short)f2bf(Vb[(size_t)(kv0 + 8 * g + e) * DH + nt * 16 + c]);
            acc[nt] = __builtin_amdgcn_mfma_f32_16x16x32_bf16(pa, vf, acc[nt], 0, 0, 0);
        }
    }
#pragma unroll
    for (int mbit = 1; mbit < 16; mbit <<= 1)
#pragma unroll
        for (int r = 0; r < 4; ++r)
            l_run[r] += __shfl_xor(l_run[r], mbit);
    float* Ob = O + ((size_t)b * NQ + q0) * DH;
#pragma unroll
    for (int r = 0; r < 4; ++r) {
        const float inv = 1.0f / l_run[r];
#pragma unroll
        for (int nt = 0; nt < 4; ++nt)
            Ob[(size_t)(4 * g + r) * DH + nt * 16 + c] = acc[nt][r] * inv;
    }
}

extern "C" void kernel_launch(void* const* d_in, const int* in_sizes, int n_in,
                              void* d_out, int out_size, void* d_ws, size_t ws_size,
                              hipStream_t stream) {
    const float* Q  = (const float*)d_in[0];
    const float* K  = (const float*)d_in[1];
    const float* V  = (const float*)d_in[2];
    const int*   VL = (const int*)d_in[3];
    float* O = (float*)d_out;

    // ws layout: Kbf 2MB | Vt 2MB | ml 1MB | Opart(bf16) 16MB  => NEED 21MB (proven fits)
    const size_t KB_OFF = 0;
    const size_t VT_OFF = (size_t)2 << 20;
    const size_t ML_OFF = (size_t)4 << 20;
    const size_t OP_OFF = (size_t)5 << 20;
    const size_t NEED   = OP_OFF + (size_t)NB * NSPLIT * 128 * 1024 * 2;

    if (ws_size >= NEED) {
        char* w = (char*)d_ws;
        unsigned short* Kbf   = (unsigned short*)(w + KB_OFF);
        unsigned short* Vtp   = (unsigned short*)(w + VT_OFF);
        float2*         mlp   = (float2*)(w + ML_OFF);
        unsigned short* Opart = (unsigned short*)(w + OP_OFF);

        prep<<<768, 256, 0, stream>>>(K, V, Kbf, Vtp);
        attn_split<<<NB * NSPLIT * 32, 256, 0, stream>>>(Q, Kbf, Vtp, VL, mlp, Opart);
        attn_merge<<<NB * 128, 64, 0, stream>>>(mlp, Opart, VL, O);
    } else {
        attn_fwd<<<NB * 128, 64, 0, stream>>>(Q, K, V, VL, O);
    }
}